// Round 12
// baseline (7849.375 us; speedup 1.0000x reference)
//
#include <hip/hip_runtime.h>

#define T_STEPS 2048
#define BATCH   256
#define ISZ     512
#define HSZ     512
#define GSZ     2048   // 4*H
#define KSZ     1024   // I + H
#define XH      1024   // LDS row stride bytes (512 bf16, swizzled, no pad)

// XOR swizzle (bits 4-6 of byte col XOR row&7).
#define SWZ(row, col) ((col) ^ (((row) & 7) << 4))

using bf16x8 = __attribute__((ext_vector_type(8))) __bf16;
using f32x4  = __attribute__((ext_vector_type(4))) float;
using i32x4  = __attribute__((ext_vector_type(4))) int;

// ---------------- workspace layout (bytes) ----------------
// 0        : W_cat  bf16 [2048][1024]        (4 MB)
// 4194304  : bias   f32  [2048]              (8 KB)
// 4202496  : thbuf0 u64  [256 rows][256]     (512 KB)  {2xbf16 h | u32 tag}
// 4726784  : thbuf1 u64  [256 rows][256]     (512 KB)

__device__ __forceinline__ unsigned short f2bf(float f) {
    unsigned int u = __float_as_uint(f);
    unsigned int r = (u + 0x7FFFu + ((u >> 16) & 1u)) >> 16;
    return (unsigned short)r;
}
__device__ __forceinline__ float bf2f(unsigned int bits16) {
    return __uint_as_float(bits16 << 16);
}
__device__ __forceinline__ float sigf(float x)   { return 1.0f / (1.0f + __expf(-x)); }
__device__ __forceinline__ float tanh_f(float x) { return 2.0f / (1.0f + __expf(-2.0f * x)) - 1.0f; }

// ---------------- pack W_ih|W_hh -> bf16 W_cat ----------------
__global__ void pack_weights(const float* __restrict__ Wih,
                             const float* __restrict__ Whh,
                             unsigned short* __restrict__ Wcat) {
    int gid = blockIdx.x * blockDim.x + threadIdx.x;   // 0 .. 524287
    int n   = gid >> 8;
    int k4  = (gid & 255) * 4;
    const float* src = (k4 < ISZ) ? (Wih + (size_t)n * ISZ + k4)
                                  : (Whh + (size_t)n * HSZ + (k4 - ISZ));
    float4 v = *(const float4*)src;
    ushort4 o;
    o.x = f2bf(v.x); o.y = f2bf(v.y); o.z = f2bf(v.z); o.w = f2bf(v.w);
    *(ushort4*)(Wcat + (size_t)n * KSZ + k4) = o;
}

// ---------------- init: tagged h buffers = 0, bias = b_ih + b_hh ----------------
__global__ void init_state(unsigned int* __restrict__ thbufs,   // both buffers, 262144 u32
                           float* __restrict__ bias,
                           const float* __restrict__ b_ih, const float* __restrict__ b_hh) {
    int gid = blockIdx.x * blockDim.x + threadIdx.x;
    if (gid < 262144) thbufs[gid] = 0u;
    if (gid < GSZ)    bias[gid] = b_ih[gid] + b_hh[gid];
}

// ---------------- persistent LSTM: 16-wave split-K/split-col pipeline ----------------
// 256 WGs x 1024 thr (16 waves, 4/SIMD). group g = bid&15 owns batch rows [g*16,+16);
// WG wgi = bid>>4 owns hidden cols [wgi*32,+32).
// wave w: gate=w&3, khalf=(w>>2)&1, colhalf=w>>3 -> 16 gate-cols x 512 K each.
// Per-wave weight fragment = wf[16] = 64 VGPRs: fits inside the compiler's 128-reg
// envelope at 4 waves/SIMD, so residency is the allocator's default (R10/R11's
// 128-reg arrays were spilled/rematerialized -> 256KB/WG/step L2 stream = the
// measured bottleneck at ~75% of L2 BW).
// Protocol/barriers identical to the proven R10 kernel: full __syncthreads(),
// self-contained probe {loads+vmcnt(0)} and publish {store+vmcnt(0)} asm.
__global__ __launch_bounds__(1024, 4) void lstm_persist(
    const float* __restrict__ x,
    const unsigned short* __restrict__ Wcat,
    const float* __restrict__ bias,
    const float* __restrict__ Wout,
    const float* __restrict__ bout,
    unsigned long long* thbuf0,
    unsigned long long* thbuf1,
    float* __restrict__ out)
{
    __shared__ __align__(16) char xlds0[16 * XH];   // x_t  bf16, double-buffered
    __shared__ __align__(16) char xlds1[16 * XH];
    __shared__ __align__(16) char hlds [16 * XH];   // h_{t-1} bf16
    __shared__ float gbuf[4][16][35];               // combined gates (padded rows)
    __shared__ float obuf[4];                       // out-dot wave partials

    const int tid  = threadIdx.x;
    const int lane = tid & 63;
    const int w    = tid >> 6;           // 0..15
    const int gate = w & 3;
    const int khalf = (w >> 2) & 1;      // 0 = x half, 1 = h half
    const int colhalf = w >> 3;          // 0..1
    const bool isx = (khalf == 0);
    const int g    = blockIdx.x & 15;
    const int wgi  = blockIdx.x >> 4;
    const int r0   = lane & 15;
    const int hi   = lane >> 4;          // 0..3

    // role-local linear index 0..511 (same formula for x-role and h-role)
    const int u = (colhalf << 8) | (gate << 6) | lane;

    // ---- W fragment: 16 k-iters x 1 col-frag = 64 VGPRs ----
    const int n0 = gate * HSZ + wgi * 32 + colhalf * 16 + r0;
    const int kb = khalf * 16;           // k-iter base
    bf16x8 wf[16];
    #pragma unroll
    for (int it = 0; it < 16; ++it)
        wf[it] = *(const bf16x8*)(Wcat + (size_t)n0 * KSZ + (kb + it) * 32 + hi * 8);
    const float bv0 = bias[n0];
    const float bo  = bout[0];

    // ---- pointwise mapping (h-role): value (row u>>5, col u&31) ----
    const int pr = u >> 5;
    const int pc = u & 31;
    float cst = 0.f;                     // cell state, 1 reg, all 2048 steps

    // ---- out-dot weights (waves 0-3: cols 2*tid, 2*tid+1) ----
    float woA = 0.f, woB = 0.f;
    if (tid < 256) { woA = Wout[tid * 2]; woB = Wout[tid * 2 + 1]; }

    // ---- tagged-h addressing ----
    const unsigned long long tb0 = (unsigned long long)thbuf0;
    const unsigned long long tb1 = (unsigned long long)thbuf1;
    // probe (h-role): row u>>5, 8 consecutive u64 at word (u&31)*8
    const unsigned long long poff =
        ((unsigned long long)(g * 16 + pr) * 256) * 8 + (unsigned)(pc * 64);
    // publish (h-role, even u): row pr, word wgi*16 + (pc>>1)
    const unsigned long long soff =
        ((unsigned long long)(g * 16 + pr) * 256 + wgi * 16 + (pc >> 1)) * 8;

    // ---- swizzle constant for fragment reads (row = r0) ----
    const int xorv = (r0 & 7) << 4;

    // ---- x prefetch regs (x-role): 4 float4 = 64B payload per thread ----
    float4 xr[4];
    const int xrow = u >> 5;             // staged row 0..15
    const int xc16 = u & 31;             // 16-float chunk within row

    // ---- prologue: stage x_0 into xlds0, prefetch x_1 ----
    if (isx) {
        const float* xb = x + ((size_t)(g * 16 + xrow)) * ISZ + xc16 * 16;
        #pragma unroll
        for (int s = 0; s < 4; ++s) xr[s] = *(const float4*)(xb + s * 4);
        char* xd = xlds0 + xrow * XH;
        #pragma unroll
        for (int s = 0; s < 4; ++s) {
            float4 v = xr[s];
            ushort4 o;
            o.x = f2bf(v.x); o.y = f2bf(v.y); o.z = f2bf(v.z); o.w = f2bf(v.w);
            *(ushort4*)(xd + SWZ(xrow, xc16 * 32 + s * 8)) = o;
        }
        const float* xb1 = x + ((size_t)BATCH + g * 16 + xrow) * ISZ + xc16 * 16;
        #pragma unroll
        for (int s = 0; s < 4; ++s) xr[s] = *(const float4*)(xb1 + s * 4);
    }
    __syncthreads();

    #pragma unroll 1
    for (int t = 0; ; ++t) {
        // ================= phase 1 =================
        if (isx) {
            if (t < T_STEPS) {
                // -- x-MFMA from xlds[t&1]: gates_x for 16 cols, K in [0,512) --
                f32x4 aa = {0.f,0.f,0.f,0.f}, ab = {0.f,0.f,0.f,0.f};
                const char* xsrc = ((t & 1) ? xlds1 : xlds0) + r0 * XH;
                #pragma unroll
                for (int it = 0; it < 16; it += 2) {
                    bf16x8 ae = *(const bf16x8*)(xsrc + ((hi * 16 + it * 64) ^ xorv));
                    bf16x8 ao = *(const bf16x8*)(xsrc + ((hi * 16 + (it + 1) * 64) ^ xorv));
                    aa = __builtin_amdgcn_mfma_f32_16x16x32_bf16(ae, wf[it],     aa, 0, 0, 0);
                    ab = __builtin_amdgcn_mfma_f32_16x16x32_bf16(ao, wf[it + 1], ab, 0, 0, 0);
                }
                #pragma unroll
                for (int j = 0; j < 4; ++j)
                    gbuf[gate][hi * 4 + j][colhalf * 16 + r0] = aa[j] + ab[j] + bv0;
                // -- stage x_{t+1}, prefetch x_{t+2} --
                if (t + 1 < T_STEPS) {
                    char* xd = (((t + 1) & 1) ? xlds1 : xlds0) + xrow * XH;
                    #pragma unroll
                    for (int s = 0; s < 4; ++s) {
                        float4 v = xr[s];
                        ushort4 o;
                        o.x = f2bf(v.x); o.y = f2bf(v.y); o.z = f2bf(v.z); o.w = f2bf(v.w);
                        *(ushort4*)(xd + SWZ(xrow, xc16 * 32 + s * 8)) = o;
                    }
                    int tp = (t + 2 < T_STEPS) ? t + 2 : T_STEPS - 1;
                    const float* xb = x + ((size_t)tp * BATCH + g * 16 + xrow) * ISZ + xc16 * 16;
                    #pragma unroll
                    for (int s = 0; s < 4; ++s) xr[s] = *(const float4*)(xb + s * 4);
                }
            }
        } else {
            char* hd = hlds + pr * XH;
            if (t == 0) {
                #pragma unroll
                for (int s = 0; s < 4; ++s)
                    *(unsigned long long*)(hd + SWZ(pr, pc * 32 + s * 8)) = 0ull;
            } else {
                // -- probe h_{t-1}: SELF-CONTAINED asm {4 loads + vmcnt(0)} --
                const unsigned long long psrc = (((t - 1) & 1) ? tb1 : tb0) + poff;
                const int tgt = t;
                i32x4 q0, q1, q2, q3;
                while (true) {
                    asm volatile(
                        "global_load_dwordx4 %0, %4, off sc0 sc1\n\t"
                        "global_load_dwordx4 %1, %4, off offset:16 sc0 sc1\n\t"
                        "global_load_dwordx4 %2, %4, off offset:32 sc0 sc1\n\t"
                        "global_load_dwordx4 %3, %4, off offset:48 sc0 sc1\n\t"
                        "s_waitcnt vmcnt(0)"
                        : "=&v"(q0), "=&v"(q1), "=&v"(q2), "=&v"(q3)
                        : "v"(psrc) : "memory");
                    bool ok = (q0[1] >= tgt) & (q0[3] >= tgt) & (q1[1] >= tgt) & (q1[3] >= tgt)
                            & (q2[1] >= tgt) & (q2[3] >= tgt) & (q3[1] >= tgt) & (q3[3] >= tgt);
                    if (__all((int)ok)) {
                        *(unsigned long long*)(hd + SWZ(pr, pc * 32 +  0)) =
                            (unsigned long long)(unsigned)q0[0] | ((unsigned long long)(unsigned)q0[2] << 32);
                        *(unsigned long long*)(hd + SWZ(pr, pc * 32 +  8)) =
                            (unsigned long long)(unsigned)q1[0] | ((unsigned long long)(unsigned)q1[2] << 32);
                        *(unsigned long long*)(hd + SWZ(pr, pc * 32 + 16)) =
                            (unsigned long long)(unsigned)q2[0] | ((unsigned long long)(unsigned)q2[2] << 32);
                        *(unsigned long long*)(hd + SWZ(pr, pc * 32 + 24)) =
                            (unsigned long long)(unsigned)q3[0] | ((unsigned long long)(unsigned)q3[2] << 32);
                        break;
                    }
                }
            }
        }
        __syncthreads();   // B2: hlds + gbuf(x half) ready

        // ================= phase 2 =================
        if (isx) {
            if (t > 0 && tid < 256) {
                // -- out[t-1] partials from hlds row wgi (waves 0-3) --
                unsigned pw2 = *(const unsigned*)(hlds + wgi * XH + (SWZ(wgi, tid * 4)));
                float ps = woA * bf2f(pw2 & 0xffffu) + woB * bf2f(pw2 >> 16);
                ps += __shfl_xor(ps, 1);
                ps += __shfl_xor(ps, 2);
                ps += __shfl_xor(ps, 4);
                ps += __shfl_xor(ps, 8);
                ps += __shfl_xor(ps, 16);
                ps += __shfl_xor(ps, 32);
                if (lane == 0) obuf[w] = ps;
            }
        } else if (t < T_STEPS) {
            // -- h-MFMA from hlds: gates_h, K in [512,1024); RMW into gbuf --
            f32x4 aa = {0.f,0.f,0.f,0.f}, ab = {0.f,0.f,0.f,0.f};
            const char* hsrc = hlds + r0 * XH;
            #pragma unroll
            for (int it = 0; it < 16; it += 2) {
                bf16x8 ae = *(const bf16x8*)(hsrc + ((hi * 16 + it * 64) ^ xorv));
                bf16x8 ao = *(const bf16x8*)(hsrc + ((hi * 16 + (it + 1) * 64) ^ xorv));
                aa = __builtin_amdgcn_mfma_f32_16x16x32_bf16(ae, wf[it],     aa, 0, 0, 0);
                ab = __builtin_amdgcn_mfma_f32_16x16x32_bf16(ao, wf[it + 1], ab, 0, 0, 0);
            }
            #pragma unroll
            for (int j = 0; j < 4; ++j)
                gbuf[gate][hi * 4 + j][colhalf * 16 + r0] += aa[j] + ab[j];
        }
        __syncthreads();   // B3: gbuf complete, obuf ready

        if (t > 0 && tid == 0)
            out[(size_t)(t - 1) * BATCH + g * 16 + wgi] =
                obuf[0] + obuf[1] + obuf[2] + obuf[3] + bo;
        if (t == T_STEPS) break;

        // ================= phase 3 (h-role: pointwise + publish) =================
        if (!isx) {
            float iv = sigf(gbuf[0][pr][pc]);
            float fv = sigf(gbuf[1][pr][pc]);
            float gv = tanh_f(gbuf[2][pr][pc]);
            float ov = sigf(gbuf[3][pr][pc]);
            cst = fv * cst + iv * gv;
            float hval = ov * tanh_f(cst);
            unsigned hb16 = (unsigned)f2bf(hval);
            unsigned partner = __shfl_xor(hb16, 1);
            if (!(u & 1)) {
                unsigned hv2 = hb16 | (partner << 16);
                unsigned long long word = (unsigned long long)hv2
                                        | ((unsigned long long)(unsigned)(t + 1) << 32);
                unsigned long long dst = ((t & 1) ? tb1 : tb0) + soff;
                // SELF-CONTAINED publish: store + drain in one asm (R10-proven).
                asm volatile("global_store_dwordx2 %0, %1, off sc0 sc1\n\t"
                             "s_waitcnt vmcnt(0)"
                             :: "v"(dst), "v"(word) : "memory");
            }
        }
        __syncthreads();   // B1: step boundary
    }
}

// ---------------- host launcher ----------------
extern "C" void kernel_launch(void* const* d_in, const int* in_sizes, int n_in,
                              void* d_out, int out_size, void* d_ws, size_t ws_size,
                              hipStream_t stream) {
    const float* x    = (const float*)d_in[0];
    const float* Wih  = (const float*)d_in[1];
    const float* Whh  = (const float*)d_in[2];
    const float* bih  = (const float*)d_in[3];
    const float* bhh  = (const float*)d_in[4];
    const float* Wout = (const float*)d_in[5];
    const float* bout = (const float*)d_in[6];

    char* ws = (char*)d_ws;
    unsigned short*     Wcat = (unsigned short*)(ws);
    float*              bias = (float*)(ws + 4194304);
    unsigned long long* th0  = (unsigned long long*)(ws + 4202496);
    unsigned long long* th1  = (unsigned long long*)(ws + 4726784);
    float*              out  = (float*)d_out;

    pack_weights<<<2048, 256, 0, stream>>>(Wih, Whh, Wcat);
    init_state<<<2048, 256, 0, stream>>>((unsigned int*)th0, bias, bih, bhh);
    lstm_persist<<<256, 1024, 0, stream>>>(x, Wcat, bias, Wout, bout, th0, th1, out);
}